// Round 3
// baseline (707.774 us; speedup 1.0000x reference)
//
#include <hip/hip_runtime.h>
#include <stdint.h>

#define NN 64
#define PLN 4096          // plane: 64 rows x 64 shorts, 16B-block XOR swizzle, no pad
#define DEG 30            // Chebyshev degree for log on [aLo, aHi]

typedef __attribute__((ext_vector_type(4))) short short4v;   // 4 bf16 = 2 VGPRs (K=8 operand)
typedef __attribute__((ext_vector_type(4))) float f32x4;
typedef __attribute__((ext_vector_type(16))) float f32x16;
typedef __attribute__((ext_vector_type(2))) unsigned int uint2v;

// K=8 MFMA: operand k = 4*(lane>>5) + e  -- matches C-layout row groups directly,
// so an accumulator can be re-fed as the next B operand with NO cross-lane exchange.
#if __has_builtin(__builtin_amdgcn_mfma_f32_32x32x8bf16_1k)
#define MFMA8(a, b, c) __builtin_amdgcn_mfma_f32_32x32x8bf16_1k((a), (b), (c), 0, 0, 0)
#else
__device__ __forceinline__ f32x16 mfma8_asm(short4v a, short4v b, f32x16 c) {
    asm("v_mfma_f32_32x32x8_bf16 %0, %1, %2, %0" : "+v"(c) : "v"(a), "v"(b));
    return c;
}
#define MFMA8(a, b, c) mfma8_asm((a), (b), (c))
#endif

__device__ __forceinline__ float ubf(uint32_t u) {
    union { uint32_t i; float f; } v; v.i = u; return v.f;
}
// packed RNE f32->bf16 x2: dst[15:0]=bf16(lo), dst[31:16]=bf16(hi)
__device__ __forceinline__ uint32_t cvtpk_bf16(float lo, float hi) {
    uint32_t r;
    asm("v_cvt_pk_bf16_f32 %0, %1, %2" : "=v"(r) : "v"(lo), "v"(hi));
    return r;
}
// split 4 f32 into hi/lo bf16 short4v (RNE hi, exact residual -> RNE lo)
__device__ __forceinline__ void split4(float v0, float v1, float v2, float v3,
                                       short4v& sh, short4v& sl) {
    uint32_t h01 = cvtpk_bf16(v0, v1);
    uint32_t h23 = cvtpk_bf16(v2, v3);
    float r0 = v0 - ubf(h01 << 16);
    float r1 = v1 - ubf(h01 & 0xFFFF0000u);
    float r2 = v2 - ubf(h23 << 16);
    float r3 = v3 - ubf(h23 & 0xFFFF0000u);
    union { uint2v u; short4v s; } a, b;
    a.u = (uint2v){h01, h23};
    b.u = (uint2v){cvtpk_bf16(r0, r1), cvtpk_bf16(r2, r3)};
    sh = a.s; sl = b.s;
}

// Pack a wave's 64x32 strip (2 C-tiles) into 8 K-slice operands, hi+lo.
// kp slice holds rows 8*kp + 4*(lane>>5) + {0..3}  == acc tile kp>>2, group kp&3.
__device__ __forceinline__ void pack_strip(const f32x16* s, short4v* bh, short4v* bl) {
#pragma unroll
    for (int kp = 0; kp < 8; ++kp) {
        const f32x16& t = s[kp >> 2];
        const int g = (kp & 3) * 4;
        split4(t[g + 0], t[g + 1], t[g + 2], t[g + 3], bh[kp], bl[kp]);
    }
}

// c{0,1} += A * strip: A-frags (2 row-tiles x 8 K-slices, hi/lo), B from packed regs.
// Split precision: ah*bh + ah*bl + al*bh.
__device__ __forceinline__ void mm48(const short4v (&ah)[2][8], const short4v (&al)[2][8],
                                     const short4v* bh, const short4v* bl,
                                     f32x16& c0, f32x16& c1) {
#pragma unroll
    for (int kp = 0; kp < 8; ++kp) {
        c0 = MFMA8(ah[0][kp], bh[kp], c0);
        c1 = MFMA8(ah[1][kp], bh[kp], c1);
        c0 = MFMA8(ah[0][kp], bl[kp], c0);
        c1 = MFMA8(ah[1][kp], bl[kp], c1);
        c0 = MFMA8(al[0][kp], bh[kp], c0);
        c1 = MFMA8(al[1][kp], bh[kp], c1);
    }
}

__global__ __launch_bounds__(128, 2)
void spdlogexp(const float* __restrict__ fin,
               const float* __restrict__ win,
               float* __restrict__ outp) {
    __shared__ __align__(16) short lds[4 * PLN];   // 32768 B
    __shared__ __align__(16) float wsh[NN];
    __shared__ float cheb[DEG + 1];

    const int tid = threadIdx.x;
    const int blk = blockIdx.x;
    const int lane = tid & 63;
    const int wv = tid >> 6;          // wave id = column-strip id: cols [32wv, 32wv+32)
    const int lh = lane >> 5;
    const int l31 = lane & 31;
    const int l7 = lane & 7;

    short* Xh = lds;
    short* Xl = lds + PLN;
    short* Yh = lds + 2 * PLN;
    short* Yl = lds + 3 * PLN;

    const float aLo = 0.09f, aHi = 6.3f;
    const float mC = 0.5f * (aLo + aHi), rC = 0.5f * (aHi - aLo);
    const float invR2 = 2.0f / rC;    // store 2T: Clenshaw's 2x folds into the A operand

    // ---- Phase 0: load X (f32, coalesced), 2T = 2(X - mC I)/rC -> hi/lo bf16 in X ----
    {
        const float4* src = (const float4*)(fin + (size_t)blk * (NN * NN));
#pragma unroll
        for (int c = 0; c < 8; ++c) {
            int v4 = c * 128 + tid;
            float4 v = src[v4];
            int e0 = v4 << 2;
            int i = e0 >> 6, j = e0 & 63;
            float t0 = (v.x - ((j + 0 == i) ? mC : 0.0f)) * invR2;
            float t1 = (v.y - ((j + 1 == i) ? mC : 0.0f)) * invR2;
            float t2 = (v.z - ((j + 2 == i) ? mC : 0.0f)) * invR2;
            float t3 = (v.w - ((j + 3 == i) ? mC : 0.0f)) * invR2;
            short4v sh, sl; split4(t0, t1, t2, t3, sh, sl);
            int idx = i * 64 + ((((j >> 3) ^ (i & 7)) << 3) | (j & 7));
            *(short4v*)(Xh + idx) = sh;
            *(short4v*)(Xl + idx) = sl;
        }
    }
    if (tid < NN) wsh[tid] = win[(size_t)blk * NN + tid];
    if (tid <= DEG) {
        // log(mC + rC t) = log(Cc) - 2 sum_k (u^k/k) T_k(t);  u<0!
        float mr = mC / rC;
        float u = -(mr - sqrtf(mr * mr - 1.0f));
        float Cc = -rC / (2.0f * u);
        if (tid == 0) cheb[0] = logf(Cc);
        else {
            float pu = powf(-u, (float)tid);          // |u|^k
            if (tid & 1) pu = -pu;                    // restore sign
            cheb[tid] = -2.0f * pu / (float)tid;
        }
    }
    __syncthreads();

    // ---- A-fragment loader (K=8 slicing): frag(q,kp) = M[32q+l31, 8kp+4lh+{0..3}] ----
    short4v fh[2][8], fl[2][8];
    auto loadfrags = [&](const short* Ph, const short* Pl) {
#pragma unroll
        for (int q = 0; q < 2; ++q)
#pragma unroll
            for (int kp = 0; kp < 8; ++kp) {
                int idx = (32 * q + l31) * 64 + ((kp ^ l7) << 3) + 4 * lh;
                fh[q][kp] = *(const short4v*)(Ph + idx);
                fl[q][kp] = *(const short4v*)(Pl + idx);
            }
    };
    loadfrags(Xh, Xl);   // 2T, cached in registers for the whole Clenshaw loop

    // ---- diag masks at C positions (tile q has diagonal only when q == wv) ----
    float dm0[16], dm1[16];
#pragma unroll
    for (int i = 0; i < 16; ++i) {
        int rp = 8 * (i >> 2) + 4 * lh + (i & 3);
        dm0[i] = (wv == 0 && rp == l31) ? 1.0f : 0.0f;
        dm1[i] = (wv == 1 && rp == l31) ? 1.0f : 0.0f;
    }

    // ---- Clenshaw, fully in registers: zero LDS, zero barriers ----
    // b_{DEG+1} = 0 (Ac), b_DEG = c_DEG I (Bc); step: dst := (ck I - dst) + 2T*pack(src)
    f32x16 Ac[2], Bc[2];
    {
        const float cD = cheb[DEG];
#pragma unroll
        for (int i = 0; i < 16; ++i) {
            Ac[0][i] = 0.0f; Ac[1][i] = 0.0f;
            Bc[0][i] = cD * dm0[i]; Bc[1][i] = cD * dm1[i];
        }
    }
    auto step = [&](f32x16* dst, const f32x16* src, float ck) {
        short4v bh[8], bl[8];
        pack_strip(src, bh, bl);
#pragma unroll
        for (int i = 0; i < 16; ++i) {
            dst[0][i] = fmaf(ck, dm0[i], -dst[0][i]);
            dst[1][i] = fmaf(ck, dm1[i], -dst[1][i]);
        }
        mm48(fh, fl, bh, bl, dst[0], dst[1]);
    };
    step(Ac, Bc, cheb[DEG - 1]);                     // k = DEG-1
    for (int k = DEG - 2; k >= 1; k -= 2) {
        step(Bc, Ac, cheb[k]);
        step(Ac, Bc, cheb[k - 1]);
    }
    // final k=0 (factor 1): Bc := 2*(c0 I - b_2) + 2T*b_1 = 2L; 0.5 folds into weights
    {
        short4v bh[8], bl[8];
        pack_strip(Ac, bh, bl);
        const float c0 = cheb[0];
#pragma unroll
        for (int i = 0; i < 16; ++i) {
            Bc[0][i] = 2.0f * fmaf(c0, dm0[i], -Bc[0][i]);
            Bc[1][i] = 2.0f * fmaf(c0, dm1[i], -Bc[1][i]);
        }
        mm48(fh, fl, bh, bl, Bc[0], Bc[1]);
    }

    // ---- A = (w_i w_j / 16) L = w_i w_j * 0.03125 * (2L)  (scaling-squaring s=4) ----
    f32x16 af[2];
    {
        const float wc = wsh[32 * wv + l31];
#pragma unroll
        for (int q = 0; q < 2; ++q)
#pragma unroll
            for (int g = 0; g < 4; ++g) {
                f32x4 w4 = *(const f32x4*)(wsh + 32 * q + 8 * g + 4 * lh);
#pragma unroll
                for (int r = 0; r < 4; ++r)
                    af[q][4 * g + r] = w4[r] * wc * 0.03125f * Bc[q][4 * g + r];
            }
    }
    __syncthreads();   // other wave's 2T frag loads complete before X is overwritten

    // strip store: transposed (symmetry) into plane rows = own cols; swizzled
    const int cC = 32 * wv + l31;
    short4v pbh[8], pbl[8];
    pack_strip(af, pbh, pbl);
#pragma unroll
    for (int kp = 0; kp < 8; ++kp) {
        int idx = cC * 64 + ((kp ^ l7) << 3) + 4 * lh;
        *(short4v*)(Xh + idx) = pbh[kp];
        *(short4v*)(Xl + idx) = pbl[kp];
    }
    __syncthreads();
    loadfrags(Xh, Xl);   // A-frags (used for both M2 = A*A and M3 = A*M2)

    // ---- M2 = A*A ----
    f32x16 m2[2];
#pragma unroll
    for (int i = 0; i < 16; ++i) { m2[0][i] = 0.0f; m2[1][i] = 0.0f; }
    mm48(fh, fl, pbh, pbl, m2[0], m2[1]);

    // ---- M3 = A*M2 ----
    short4v qbh[8], qbl[8];
    pack_strip(m2, qbh, qbl);
    f32x16 m3[2];
#pragma unroll
    for (int i = 0; i < 16; ++i) { m3[0][i] = 0.0f; m3[1][i] = 0.0f; }
    mm48(fh, fl, qbh, qbl, m3[0], m3[1]);

    // ---- b0 (into m2), G (into af) ----
#pragma unroll
    for (int q = 0; q < 2; ++q)
#pragma unroll
        for (int i = 0; i < 16; ++i) {
            float d = q ? dm1[i] : dm0[i];
            float a = af[q][i], m2v = m2[q][i], m3v = m3[q][i];
            m2[q][i] = d + a + 0.5f * m2v;                       // b0
            af[q][i] = (1.0f / 6.0f) * d + (1.0f / 24.0f) * a +
                       (1.0f / 120.0f) * m2v + (1.0f / 720.0f) * m3v;   // G
        }

    // ---- store G -> Y, P = b0 + G*M3 ----
    pack_strip(af, pbh, pbl);
#pragma unroll
    for (int kp = 0; kp < 8; ++kp) {
        int idx = cC * 64 + ((kp ^ l7) << 3) + 4 * lh;
        *(short4v*)(Yh + idx) = pbh[kp];
        *(short4v*)(Yl + idx) = pbl[kp];
    }
    __syncthreads();
    loadfrags(Yh, Yl);                   // G-frags
    pack_strip(m3, qbh, qbl);            // B = M3
    mm48(fh, fl, qbh, qbl, m2[0], m2[1]);   // m2 = b0 + G*M3 = P

    // ---- 4 squarings: exp(M) = P^16.  store->X,Y,X,Y; B always own strip pack ----
#pragma unroll
    for (int it = 0; it < 4; ++it) {
        pack_strip(m2, pbh, pbl);
        short* Dh = (it & 1) ? Yh : Xh;
        short* Dl = (it & 1) ? Yl : Xl;
#pragma unroll
        for (int kp = 0; kp < 8; ++kp) {
            int idx = cC * 64 + ((kp ^ l7) << 3) + 4 * lh;
            *(short4v*)(Dh + idx) = pbh[kp];
            *(short4v*)(Dl + idx) = pbl[kp];
        }
        __syncthreads();
        loadfrags(Dh, Dl);
        f32x16 n0, n1;
#pragma unroll
        for (int i = 0; i < 16; ++i) { n0[i] = 0.0f; n1[i] = 0.0f; }
        mm48(fh, fl, pbh, pbl, n0, n1);
        m2[0] = n0; m2[1] = n1;
    }

    // ---- stage transposed f32 over X region (16 KB, disjoint from Y being read) ----
    {
        float* stg = (float*)lds;
#pragma unroll
        for (int q = 0; q < 2; ++q)
#pragma unroll
            for (int g = 0; g < 4; ++g) {
                f32x4 v;
#pragma unroll
                for (int r = 0; r < 4; ++r) v[r] = m2[q][4 * g + r];
                int bblk = 8 * q + 2 * g + lh;
                *(f32x4*)(stg + cC * 64 + ((bblk ^ l7) << 2)) = v;
            }
    }
    __syncthreads();

    // ---- coalesced float4 store (swizzled staging read; out = C^T = C by symmetry) ----
    {
        const float* stg = (const float*)lds;
        float4* dst = (float4*)(outp + (size_t)blk * (NN * NN));
#pragma unroll
        for (int c = 0; c < 8; ++c) {
            int v4 = c * 128 + tid;
            int i = v4 >> 4, jb = v4 & 15;
            f32x4 v = *(const f32x4*)(stg + i * 64 + ((jb ^ (i & 7)) << 2));
            float4 o; o.x = v[0]; o.y = v[1]; o.z = v[2]; o.w = v[3];
            dst[v4] = o;
        }
    }
}

extern "C" void kernel_launch(void* const* d_in, const int* in_sizes, int n_in,
                              void* d_out, int out_size, void* d_ws, size_t ws_size,
                              hipStream_t stream) {
    const float* f = (const float*)d_in[0];
    const float* w = (const float*)d_in[1];
    float* o = (float*)d_out;
    int B = in_sizes[0] / (NN * NN);
    spdlogexp<<<dim3(B), dim3(128), 0, stream>>>(f, w, o);
}

// Round 4
// 542.460 us; speedup vs baseline: 1.3047x; 1.3047x over previous
//
#include <hip/hip_runtime.h>
#include <stdint.h>

#define NN 64
#define PLN 4096          // plane: 64 rows x 64 shorts, 16B-block XOR swizzle, no pad
#define DEG 30            // Chebyshev degree for log on [aLo, aHi]

typedef __attribute__((ext_vector_type(8))) short short8;    // 8 bf16 = 4 VGPRs (K=16 operand)
typedef __attribute__((ext_vector_type(4))) float f32x4;
typedef __attribute__((ext_vector_type(16))) float f32x16;
typedef __attribute__((ext_vector_type(4))) unsigned int uint4v;

#define MFMA16(a, b, c) __builtin_amdgcn_mfma_f32_32x32x16_bf16((a), (b), (c), 0, 0, 0)

__device__ __forceinline__ float ubf(uint32_t u) {
    union { uint32_t i; float f; } v; v.i = u; return v.f;
}
// packed RNE f32->bf16 x2: dst[15:0]=bf16(lo arg), dst[31:16]=bf16(hi arg)
__device__ __forceinline__ uint32_t cvtpk_bf16(float lo, float hi) {
    uint32_t r;
    asm("v_cvt_pk_bf16_f32 %0, %1, %2" : "=v"(r) : "v"(lo), "v"(hi));
    return r;
}
// v_permlane32_swap_b32 a, b:  a' = {a.lo_half, b.lo_half}, b' = {a.hi_half, b.hi_half}
__device__ __forceinline__ void plswap(uint32_t& a, uint32_t& b) {
    asm("v_permlane32_swap_b32 %0, %1" : "+v"(a), "+v"(b));
}
__device__ __forceinline__ short8 u4s8(uint32_t a, uint32_t b, uint32_t c, uint32_t d) {
    union { uint4v u; short8 s; } t; t.u = (uint4v){a, b, c, d}; return t.s;
}

// Split a wave's 64x32 strip (2 C-tiles, f32) into 16 hi + 16 lo packed bf16 words.
// Word q*8 + 2g + p holds rows 32q + 8g + 4*(lane>>5) + {2p, 2p+1} at col = own col.
__device__ __forceinline__ void mk_words(const f32x16& s0, const f32x16& s1,
                                         uint32_t* wh, uint32_t* wl) {
#pragma unroll
    for (int q = 0; q < 2; ++q) {
        const f32x16& s = q ? s1 : s0;
#pragma unroll
        for (int j = 0; j < 8; ++j) {
            float v0 = s[2 * j], v1 = s[2 * j + 1];
            uint32_t h = cvtpk_bf16(v0, v1);
            float r0 = v0 - ubf(h << 16);
            float r1 = v1 - ubf(h & 0xFFFF0000u);
            wh[q * 8 + j] = h;
            wl[q * 8 + j] = cvtpk_bf16(r0, r1);
        }
    }
}

// Rearrange packed words into K=16 B-operand fragments via permlane32_swap.
// Frag kk=2q+s word m=p / m=2+p come from one swap of (w[q][2s][p], w[q][2s+1][p]).
__device__ __forceinline__ void words_to_frags(const uint32_t* wh, const uint32_t* wl,
                                               short8* bh, short8* bl) {
#pragma unroll
    for (int q = 0; q < 2; ++q)
#pragma unroll
        for (int s2 = 0; s2 < 2; ++s2) {
            uint32_t a0 = wh[q * 8 + 4 * s2 + 0], b0 = wh[q * 8 + 4 * s2 + 2];
            uint32_t a1 = wh[q * 8 + 4 * s2 + 1], b1 = wh[q * 8 + 4 * s2 + 3];
            plswap(a0, b0); plswap(a1, b1);
            bh[2 * q + s2] = u4s8(a0, a1, b0, b1);
            uint32_t c0 = wl[q * 8 + 4 * s2 + 0], d0 = wl[q * 8 + 4 * s2 + 2];
            uint32_t c1 = wl[q * 8 + 4 * s2 + 1], d1 = wl[q * 8 + 4 * s2 + 3];
            plswap(c0, d0); plswap(c1, d1);
            bl[2 * q + s2] = u4s8(c0, c1, d0, d1);
        }
}

// Store own strip transposed (symmetry) into plane: row = own col cC, cols 32q+8g+4lh+{0..3}
__device__ __forceinline__ void store_words(short* Ph, short* Pl,
                                            const uint32_t* wh, const uint32_t* wl,
                                            int cC, int lh, int l7) {
#pragma unroll
    for (int q = 0; q < 2; ++q)
#pragma unroll
        for (int g = 0; g < 4; ++g) {
            int idx = cC * 64 + ((((4 * q + g) ^ l7)) << 3) + 4 * lh;
            uint2 vh; vh.x = wh[q * 8 + g * 2]; vh.y = wh[q * 8 + g * 2 + 1];
            *(uint2*)(Ph + idx) = vh;
            uint2 vl; vl.x = wl[q * 8 + g * 2]; vl.y = wl[q * 8 + g * 2 + 1];
            *(uint2*)(Pl + idx) = vl;
        }
}

// c0/c1 += A * strip, split precision (ah*bh + ah*bl + al*bh), K=64 over 4 chunks.
__device__ __forceinline__ void mm24(const short8 (&ah)[2][4], const short8 (&al)[2][4],
                                     const short8* bh, const short8* bl,
                                     f32x16& c0, f32x16& c1) {
#pragma unroll
    for (int kk = 0; kk < 4; ++kk) {
        c0 = MFMA16(ah[0][kk], bh[kk], c0);
        c1 = MFMA16(ah[1][kk], bh[kk], c1);
        c0 = MFMA16(ah[0][kk], bl[kk], c0);
        c1 = MFMA16(ah[1][kk], bl[kk], c1);
        c0 = MFMA16(al[0][kk], bh[kk], c0);
        c1 = MFMA16(al[1][kk], bh[kk], c1);
    }
}

__global__ __launch_bounds__(128, 2)
void spdlogexp(const float* __restrict__ fin,
               const float* __restrict__ win,
               float* __restrict__ outp) {
    __shared__ __align__(16) short lds[2 * PLN];   // 16384 B: single X buffer (hi, lo)
    __shared__ __align__(16) float wsh[NN];
    __shared__ float cheb[DEG + 1];

    const int tid = threadIdx.x;
    const int blk = blockIdx.x;
    const int lane = tid & 63;
    const int wv = tid >> 6;          // wave id = column-strip: cols [32wv, 32wv+32)
    const int lh = lane >> 5;
    const int l31 = lane & 31;
    const int l7 = lane & 7;
    const int cC = 32 * wv + l31;     // own column

    short* Xh = lds;
    short* Xl = lds + PLN;

    const float aLo = 0.09f, aHi = 6.3f;
    const float mC = 0.5f * (aLo + aHi), rC = 0.5f * (aHi - aLo);
    const float invR2 = 2.0f / rC;    // store 2T: Clenshaw's 2x folds into the A operand

    // ---- Phase 0: load X (f32, coalesced), 2T = 2(X - mC I)/rC -> hi/lo bf16 in X ----
    {
        const float4* src = (const float4*)(fin + (size_t)blk * (NN * NN));
#pragma unroll
        for (int c = 0; c < 8; ++c) {
            int v4 = c * 128 + tid;
            float4 v = src[v4];
            int e0 = v4 << 2;
            int i = e0 >> 6, j = e0 & 63;
            float t0 = (v.x - ((j + 0 == i) ? mC : 0.0f)) * invR2;
            float t1 = (v.y - ((j + 1 == i) ? mC : 0.0f)) * invR2;
            float t2 = (v.z - ((j + 2 == i) ? mC : 0.0f)) * invR2;
            float t3 = (v.w - ((j + 3 == i) ? mC : 0.0f)) * invR2;
            uint32_t h01 = cvtpk_bf16(t0, t1);
            uint32_t h23 = cvtpk_bf16(t2, t3);
            float r0 = t0 - ubf(h01 << 16);
            float r1 = t1 - ubf(h01 & 0xFFFF0000u);
            float r2 = t2 - ubf(h23 << 16);
            float r3 = t3 - ubf(h23 & 0xFFFF0000u);
            int idx = i * 64 + ((((j >> 3) ^ (i & 7)) << 3) | (j & 7));
            uint2 ph; ph.x = h01; ph.y = h23;
            uint2 pl; pl.x = cvtpk_bf16(r0, r1); pl.y = cvtpk_bf16(r2, r3);
            *(uint2*)(Xh + idx) = ph;
            *(uint2*)(Xl + idx) = pl;
        }
    }
    if (tid < NN) wsh[tid] = win[(size_t)blk * NN + tid];
    if (tid <= DEG) {
        // log(mC + rC t) = log(Cc) - 2 sum_k (u^k/k) T_k(t);  u<0!
        float mr = mC / rC;
        float u = -(mr - sqrtf(mr * mr - 1.0f));
        float Cc = -rC / (2.0f * u);
        if (tid == 0) cheb[0] = logf(Cc);
        else {
            float pu = powf(-u, (float)tid);          // |u|^k
            if (tid & 1) pu = -pu;                    // restore sign
            cheb[tid] = -2.0f * pu / (float)tid;
        }
    }
    __syncthreads();

    // ---- A-fragment loader: frag(q,kk) = M[32q+l31, 16kk+8lh+{0..7}] (swizzled) ----
    short8 th[2][4], tl[2][4];
    auto loadfrags = [&](const short* Ph, const short* Pl) {
#pragma unroll
        for (int q = 0; q < 2; ++q)
#pragma unroll
            for (int kk = 0; kk < 4; ++kk) {
                int idx = (32 * q + l31) * 64 + (((2 * kk + lh) ^ l7) << 3);
                th[q][kk] = *(const short8*)(Ph + idx);
                tl[q][kk] = *(const short8*)(Pl + idx);
            }
    };
    loadfrags(Xh, Xl);   // 2T, register-cached for the whole Clenshaw recursion

    // ---- diag mask (within-tile) + tile selectors (wave-uniform) ----
    float dm[16];
#pragma unroll
    for (int i = 0; i < 16; ++i) {
        int rp = 8 * (i >> 2) + 4 * lh + (i & 3);
        dm[i] = (rp == l31) ? 1.0f : 0.0f;
    }
    const float ds0 = (wv == 0) ? 1.0f : 0.0f;
    const float ds1 = 1.0f - ds0;

    // ---- Clenshaw, fully in registers: zero LDS, zero barriers ----
    f32x16 A0, A1, B0, B1;
    {
        const float cD = cheb[DEG];
#pragma unroll
        for (int i = 0; i < 16; ++i) {
            A0[i] = 0.0f; A1[i] = 0.0f;          // b_{DEG+1}
            B0[i] = cD * dm[i] * ds0;            // b_DEG = c_DEG I
            B1[i] = cD * dm[i] * ds1;
        }
    }
    // step: dst := (ck I - dst) + 2T * pack(src)
    auto clen = [&](f32x16& x0, f32x16& x1, const f32x16& y0, const f32x16& y1, float ck) {
        uint32_t wwh[16], wwl[16];
        short8 bh[4], bl[4];
        mk_words(y0, y1, wwh, wwl);
        words_to_frags(wwh, wwl, bh, bl);
        const float c0v = ck * ds0, c1v = ck * ds1;
#pragma unroll
        for (int i = 0; i < 16; ++i) {
            x0[i] = fmaf(c0v, dm[i], -x0[i]);
            x1[i] = fmaf(c1v, dm[i], -x1[i]);
        }
        mm24(th, tl, bh, bl, x0, x1);
    };
    clen(A0, A1, B0, B1, cheb[DEG - 1]);         // k = DEG-1
#pragma unroll 1
    for (int k = DEG - 2; k >= 1; k -= 2) {
        clen(B0, B1, A0, A1, cheb[k]);
        clen(A0, A1, B0, B1, cheb[k - 1]);
    }
    // final k=0 (factor 1): B := 2*(c0 I - b_2) + 2T*b_1 = 2L; 0.5 folds into weights
    {
        uint32_t wwh[16], wwl[16];
        short8 bh[4], bl[4];
        mk_words(A0, A1, wwh, wwl);
        words_to_frags(wwh, wwl, bh, bl);
        const float c00 = cheb[0] * ds0, c01 = cheb[0] * ds1;
#pragma unroll
        for (int i = 0; i < 16; ++i) {
            B0[i] = 2.0f * fmaf(c00, dm[i], -B0[i]);
            B1[i] = 2.0f * fmaf(c01, dm[i], -B1[i]);
        }
        mm24(th, tl, bh, bl, B0, B1);
    }

    // ---- A = (w_i w_j / 16) L = w_i w_j * 0.03125 * (2L)  (scaling-squaring s=4) ----
    f32x16 aF0, aF1;
    {
        const float wc = wsh[cC] * 0.03125f;
#pragma unroll
        for (int g = 0; g < 4; ++g) {
            f32x4 w40 = *(const f32x4*)(wsh + 8 * g + 4 * lh);
            f32x4 w41 = *(const f32x4*)(wsh + 32 + 8 * g + 4 * lh);
#pragma unroll
            for (int r = 0; r < 4; ++r) {
                aF0[4 * g + r] = w40[r] * wc * B0[4 * g + r];
                aF1[4 * g + r] = w41[r] * wc * B1[4 * g + r];
            }
        }
    }
    __syncthreads();   // partner finished its 2T frag loads long ago; X now writable

    uint32_t wwh[16], wwl[16];
    short8 pb[4], plo[4];
    // ---- store A -> X; M2 = A*A (B = own pack) ----
    mk_words(aF0, aF1, wwh, wwl);
    store_words(Xh, Xl, wwh, wwl, cC, lh, l7);
    words_to_frags(wwh, wwl, pb, plo);
    __syncthreads();
    loadfrags(Xh, Xl);                 // A-frags (overwrite 2T frags)
    f32x16 m20, m21;
#pragma unroll
    for (int i = 0; i < 16; ++i) { m20[i] = 0.0f; m21[i] = 0.0f; }
    mm24(th, tl, pb, plo, m20, m21);
    // ---- M3 = A*M2 (B = pack(M2), no LDS) ----
    mk_words(m20, m21, wwh, wwl);
    words_to_frags(wwh, wwl, pb, plo);
    f32x16 m30, m31;
#pragma unroll
    for (int i = 0; i < 16; ++i) { m30[i] = 0.0f; m31[i] = 0.0f; }
    mm24(th, tl, pb, plo, m30, m31);
    // ---- b0 = I + A + M2/2 ; G = I/6 + A/24 + M2/120 + M3/720 ----
    f32x16 b00, b01, g0, g1;
#pragma unroll
    for (int i = 0; i < 16; ++i) {
        float d0 = dm[i] * ds0, d1 = dm[i] * ds1;
        b00[i] = d0 + aF0[i] + 0.5f * m20[i];
        b01[i] = d1 + aF1[i] + 0.5f * m21[i];
        g0[i] = (1.0f / 6.0f) * d0 + (1.0f / 24.0f) * aF0[i] +
                (1.0f / 120.0f) * m20[i] + (1.0f / 720.0f) * m30[i];
        g1[i] = (1.0f / 6.0f) * d1 + (1.0f / 24.0f) * aF1[i] +
                (1.0f / 120.0f) * m21[i] + (1.0f / 720.0f) * m31[i];
    }
    __syncthreads();   // partner done loading A-frags; X writable
    // ---- store G -> X; P = b0 + G*M3 (acc seeded with b0) ----
    mk_words(g0, g1, wwh, wwl);
    store_words(Xh, Xl, wwh, wwl, cC, lh, l7);
    mk_words(m30, m31, wwh, wwl);
    words_to_frags(wwh, wwl, pb, plo);   // B = M3
    __syncthreads();
    loadfrags(Xh, Xl);                   // G-frags
    mm24(th, tl, pb, plo, b00, b01);     // b0 + G*M3 = P

    // ---- 4 squarings: exp(M) = P^16 ----
#pragma unroll 1
    for (int it = 0; it < 4; ++it) {
        __syncthreads();                 // partner done loading previous frags from X
        mk_words(b00, b01, wwh, wwl);
        store_words(Xh, Xl, wwh, wwl, cC, lh, l7);
        words_to_frags(wwh, wwl, pb, plo);
        __syncthreads();
        loadfrags(Xh, Xl);
        f32x16 n0, n1;
#pragma unroll
        for (int i = 0; i < 16; ++i) { n0[i] = 0.0f; n1[i] = 0.0f; }
        mm24(th, tl, pb, plo, n0, n1);
        b00 = n0; b01 = n1;
    }

    // ---- stage transposed f32 over X region (16 KB exactly), swizzled ----
    __syncthreads();                     // partner done with final frag loads
    {
        float* stg = (float*)lds;
#pragma unroll
        for (int q = 0; q < 2; ++q)
#pragma unroll
            for (int g = 0; g < 4; ++g) {
                const f32x16& srcv = q ? b01 : b00;
                f32x4 v;
#pragma unroll
                for (int r = 0; r < 4; ++r) v[r] = srcv[4 * g + r];
                int bblk = 8 * q + 2 * g + lh;
                *(f32x4*)(stg + cC * 64 + ((bblk ^ l7) << 2)) = v;
            }
    }
    __syncthreads();

    // ---- coalesced float4 store (out = C^T = C by symmetry) ----
    {
        const float* stg = (const float*)lds;
        float4* dst = (float4*)(outp + (size_t)blk * (NN * NN));
#pragma unroll
        for (int c = 0; c < 8; ++c) {
            int v4 = c * 128 + tid;
            int i = v4 >> 4, jb = v4 & 15;
            f32x4 v = *(const f32x4*)(stg + i * 64 + ((jb ^ (i & 7)) << 2));
            float4 o; o.x = v[0]; o.y = v[1]; o.z = v[2]; o.w = v[3];
            dst[v4] = o;
        }
    }
}

extern "C" void kernel_launch(void* const* d_in, const int* in_sizes, int n_in,
                              void* d_out, int out_size, void* d_ws, size_t ws_size,
                              hipStream_t stream) {
    const float* f = (const float*)d_in[0];
    const float* w = (const float*)d_in[1];
    float* o = (float*)d_out;
    int B = in_sizes[0] / (NN * NN);
    spdlogexp<<<dim3(B), dim3(128), 0, stream>>>(f, w, o);
}